// Round 5
// baseline (314.431 us; speedup 1.0000x reference)
//
#include <hip/hip_runtime.h>
#include <cstdint>
#include <cstddef>

// Problem constants (MultiHeadAttention: B=4, T=2048, d_model=1024, H=16, hd=64)
#define D_MODEL 1024
#define SEQQ    2048
#define NBATCH  4
#define NHEAD   16
#define HDIM    64
#define MTOT    (NBATCH * SEQQ)   // 8192 rows

typedef __attribute__((ext_vector_type(8))) short short8;   // 8 x bf16 (4 VGPRs) — MFMA A/B frag
typedef __attribute__((ext_vector_type(4))) float floatx4;  // MFMA C/D frag
typedef unsigned short u16;                                  // bf16 bits

__device__ __forceinline__ u16 f2bf(float f) {
  union { float f; uint32_t u; } a; a.f = f;
  uint32_t u = a.u;
  u += 0x7fffu + ((u >> 16) & 1u);   // RN-even
  return (u16)(u >> 16);
}

__device__ __forceinline__ floatx4 mfma16(short8 a, short8 b, floatx4 c) {
  return __builtin_amdgcn_mfma_f32_16x16x32_bf16(a, b, c, 0, 0, 0);
}

// async global->LDS, 16B per lane. LDS dest = wave-uniform base + lane*16.
__device__ __forceinline__ void load_lds16(const void* g, void* l) {
  __builtin_amdgcn_global_load_lds(
      (const __attribute__((address_space(1))) uint32_t*)g,
      (__attribute__((address_space(3))) uint32_t*)l, 16, 0, 0);
}

// ---------------------------------------------------------------- fused casts f32->bf16
// blocks [0, 8192): X (8.4M elems). blocks [8192, 12288): weights, 1024 blocks each.
__global__ __launch_bounds__(256) void k_cast_all(
    const float* __restrict__ X, const float* __restrict__ w0,
    const float* __restrict__ w1, const float* __restrict__ w2,
    const float* __restrict__ w3,
    u16* __restrict__ xb, u16* __restrict__ y0, u16* __restrict__ y1,
    u16* __restrict__ y2, u16* __restrict__ y3) {
  const int bx = blockIdx.x;
  const float* src; u16* dst; int i;
  if (bx < 8192) {
    src = X; dst = xb; i = (bx * 256 + threadIdx.x) * 4;
  } else {
    const int w = (bx - 8192) >> 10;
    src = (w == 0) ? w0 : (w == 1) ? w1 : (w == 2) ? w2 : w3;
    dst = (w == 0) ? y0 : (w == 1) ? y1 : (w == 2) ? y2 : y3;
    i = (((bx - 8192) & 1023) * 256 + threadIdx.x) * 4;
  }
  float4 v = *(const float4*)(src + i);
  ushort4 o;
  o.x = f2bf(v.x); o.y = f2bf(v.y); o.z = f2bf(v.z); o.w = f2bf(v.w);
  *(ushort4*)(dst + i) = o;
}

// ---------------------------------------------------------------- GEMM  C = A @ B^T (+bias)
// ascaleQ: extra scale on the z==0 output (folds 1/sqrt(hd)*log2e into Q).
__global__ __launch_bounds__(256) void k_gemm_bt(
    const u16* __restrict__ A,
    const u16* __restrict__ B0, const u16* __restrict__ B1, const u16* __restrict__ B2,
    void* __restrict__ C0, void* __restrict__ C1, void* __restrict__ C2,
    const float* __restrict__ bias, int M, int N, int K, int f32out, float ascaleQ) {
  __shared__ __align__(16) u16 As[128 * 64];
  __shared__ __align__(16) u16 Bs[128 * 64];
  const int tid = threadIdx.x;
  const int lane = tid & 63, wave = tid >> 6;
  const int quad = lane >> 4, l15 = lane & 15;
  const int m0 = blockIdx.y * 128, n0 = blockIdx.x * 128;
  const int wr = wave >> 1, wc = wave & 1;
  const u16* Bm = (blockIdx.z == 0) ? B0 : (blockIdx.z == 1 ? B1 : B2);
  void* Cm = (blockIdx.z == 0) ? C0 : (blockIdx.z == 1 ? C1 : C2);
  const float ascale = (blockIdx.z == 0) ? ascaleQ : 1.0f;

  floatx4 acc[4][4];
#pragma unroll
  for (int i = 0; i < 4; ++i)
#pragma unroll
    for (int j = 0; j < 4; ++j) acc[i][j] = (floatx4){0.f, 0.f, 0.f, 0.f};

  const int srow = tid >> 3;                       // 0..31
  const int scolx = ((tid & 7) * 8) ^ ((srow & 7) * 8);  // swizzled source column
  const u16* Ag = A + (size_t)(m0 + srow) * K + scolx;
  const u16* Bg = Bm + (size_t)(n0 + srow) * K + scolx;

  for (int kt = 0; kt < K; kt += 64) {
    __syncthreads();
#pragma unroll
    for (int p = 0; p < 4; ++p) {
      load_lds16(Ag + (size_t)(p * 32) * K + kt, &As[p * 2048 + wave * 512]);
      load_lds16(Bg + (size_t)(p * 32) * K + kt, &Bs[p * 2048 + wave * 512]);
    }
    __syncthreads();

    short8 af[2][4], bfg[2][4];
#pragma unroll
    for (int ks = 0; ks < 2; ++ks) {
      const int kkx = (ks * 32 + quad * 8) ^ ((l15 & 7) * 8);
#pragma unroll
      for (int i = 0; i < 4; ++i) {
        af[ks][i]  = *(const short8*)&As[(wr * 64 + i * 16 + l15) * 64 + kkx];
        bfg[ks][i] = *(const short8*)&Bs[(wc * 64 + i * 16 + l15) * 64 + kkx];
      }
    }
#pragma unroll
    for (int ks = 0; ks < 2; ++ks)
#pragma unroll
      for (int mi = 0; mi < 4; ++mi)
#pragma unroll
        for (int ni = 0; ni < 4; ++ni)
          acc[mi][ni] = mfma16(af[ks][mi], bfg[ks][ni], acc[mi][ni]);
  }

  // Epilogue. C/D layout: col = lane&15, row = quad*4 + reg (m89-verified).
#pragma unroll
  for (int mi = 0; mi < 4; ++mi) {
#pragma unroll
    for (int ni = 0; ni < 4; ++ni) {
      const int row = m0 + wr * 64 + mi * 16 + quad * 4;
      const int col = n0 + wc * 64 + ni * 16 + l15;
      const float bv = bias ? bias[col] : 0.f;
#pragma unroll
      for (int r = 0; r < 4; ++r) {
        const float v = acc[mi][ni][r] * ascale + bv;
        if (f32out) ((float*)Cm)[(size_t)(row + r) * N + col] = v;
        else        ((u16*)Cm)[(size_t)(row + r) * N + col] = f2bf(v);
      }
    }
  }
}

// ---------------------------------------------------------------- V transpose
__global__ __launch_bounds__(256) void k_transpose_v(const u16* __restrict__ Vb,
                                                     u16* __restrict__ Vt) {
  __shared__ u16 tile[64][65];
  const int tid = threadIdx.x;
  const int bh = blockIdx.y, b = bh >> 4, h = bh & 15;
  const int t0 = blockIdx.x * 64;
  const int r = tid >> 2;             // 0..63
  const int c0 = (tid & 3) * 16;      // 0,16,32,48
  const u16* src = Vb + (size_t)(b * SEQQ + t0 + r) * D_MODEL + h * HDIM + c0;
  short8 v0 = *(const short8*)(src);
  short8 v1 = *(const short8*)(src + 8);
#pragma unroll
  for (int j = 0; j < 8; ++j) {
    tile[r][c0 + j]     = ((const u16*)&v0)[j];
    tile[r][c0 + 8 + j] = ((const u16*)&v1)[j];
  }
  __syncthreads();
  const int d = tid >> 2;
  const int tc = (tid & 3) * 16;
  u16 tmp[16];
#pragma unroll
  for (int j = 0; j < 16; ++j) tmp[j] = tile[tc + j][d];
  u16* dst = Vt + ((size_t)bh * HDIM + d) * SEQQ + t0 + tc;
  *(short8*)(dst)     = *(const short8*)&tmp[0];
  *(short8*)(dst + 8) = *(const short8*)&tmp[8];
}

// ---------------------------------------------------------------- flash attention
// Paired q-tiles (p, 15-p) at 128-row granularity; 4 waves x 32 q-rows each
// (2 sub-tiles of 16). Key-tile 64 staged once per iter, kf/vf fragments
// reused by 4 subtile-computes -> staging+barrier+ds_read per score halves
// vs 16-row waves. S^T = K·Q^T (lane = one query), static-max softmax,
// per-lane l, zero shuffles in loop. P packed to bf16 via v_perm_b32 (RTZ,
// 2 values/instr) and round-tripped through per-wave LDS.
__device__ __forceinline__ void softmax_pv_T(
    floatx4 (&st)[4], float& lp, floatx4 (&acc)[4],
    u16* psw, const short8 (&vf)[2][4], int quad, int l15, int mi) {
  const int row = mi * 16 + l15;
#pragma unroll
  for (int ni = 0; ni < 4; ++ni) {
    const float p0 = __builtin_amdgcn_exp2f(st[ni][0]);
    const float p1 = __builtin_amdgcn_exp2f(st[ni][1]);
    const float p2 = __builtin_amdgcn_exp2f(st[ni][2]);
    const float p3 = __builtin_amdgcn_exp2f(st[ni][3]);
    lp += (p0 + p1) + (p2 + p3);
    uint2 pk;
    pk.x = __builtin_amdgcn_perm(__float_as_uint(p1), __float_as_uint(p0), 0x07060302u);
    pk.y = __builtin_amdgcn_perm(__float_as_uint(p3), __float_as_uint(p2), 0x07060302u);
    *(uint2*)&psw[row * 72 + ni * 16 + quad * 4] = pk;   // [q][key], 8B store
  }
  asm volatile("s_waitcnt lgkmcnt(0)" ::: "memory");  // P visible (intra-wave DS order)
#pragma unroll
  for (int kc = 0; kc < 2; ++kc) {
    const short8 pf = *(const short8*)&psw[row * 72 + kc * 32 + quad * 8];
#pragma unroll
    for (int di = 0; di < 4; ++di)
      acc[di] = mfma16(pf, vf[kc][di], acc[di]);
  }
}

__global__ __launch_bounds__(256) void k_attn(
    const u16* __restrict__ Q, const u16* __restrict__ Kg,
    const u16* __restrict__ Vt, u16* __restrict__ O) {
  __shared__ __align__(16) u16 Ks[64 * 64];
  __shared__ __align__(16) u16 Vs[64 * 64];
  __shared__ __align__(16) u16 Ps[4][32 * 72];   // per-wave P^T as [q][key], pad 72
  const int tid = threadIdx.x, lane = tid & 63, wave = tid >> 6;
  const int quad = lane >> 4, l15 = lane & 15;
  const int bh = blockIdx.y, b = bh >> 4, h = bh & 15;
  const int p = blockIdx.x;                    // pair index 0..7
  const int qwA = 128 * p + wave * 32;
  const int qwB = SEQQ - 128 * (p + 1) + wave * 32;
  const int nT = 32 - 2 * p;                   // 64-key tiles for B (>= A's need)

  const u16* kbase = Kg + (size_t)(b * SEQQ) * D_MODEL + h * HDIM;
  const u16* vbase = Vt + (size_t)bh * (HDIM * SEQQ);

  // Q fragments ([idx=l15][k=quad*8+j]); Q pre-scaled by 1/sqrt(hd)*log2e.
  short8 qfA[2][2], qfB[2][2];
#pragma unroll
  for (int mi = 0; mi < 2; ++mi) {
    const u16* qa = Q + (size_t)(b * SEQQ + qwA + mi * 16 + l15) * D_MODEL + h * HDIM;
    const u16* qb = Q + (size_t)(b * SEQQ + qwB + mi * 16 + l15) * D_MODEL + h * HDIM;
#pragma unroll
    for (int ks = 0; ks < 2; ++ks) {
      qfA[mi][ks] = *(const short8*)(qa + ks * 32 + quad * 8);
      qfB[mi][ks] = *(const short8*)(qb + ks * 32 + quad * 8);
    }
  }

  floatx4 accA[2][4], accB[2][4];
  float lpA[2] = {0.f, 0.f}, lpB[2] = {0.f, 0.f};
#pragma unroll
  for (int mi = 0; mi < 2; ++mi)
#pragma unroll
    for (int i = 0; i < 4; ++i) {
      accA[mi][i] = (floatx4){0.f, 0.f, 0.f, 0.f};
      accB[mi][i] = (floatx4){0.f, 0.f, 0.f, 0.f};
    }

  const int srow = tid >> 3;                            // 0..31
  const int scol = ((tid & 7) * 8) ^ ((srow & 7) * 8);  // swizzled col 0..63
  u16* psw = &Ps[wave][0];

  for (int t = 0; t < nT; ++t) {
    const int kt = t * 64;
    __syncthreads();   // protect previous iter's LDS reads
    load_lds16(kbase + (size_t)(kt + srow) * D_MODEL + scol,      &Ks[wave * 512]);
    load_lds16(kbase + (size_t)(kt + 32 + srow) * D_MODEL + scol, &Ks[2048 + wave * 512]);
    load_lds16(vbase + (size_t)srow * SEQQ + kt + scol,           &Vs[wave * 512]);
    load_lds16(vbase + (size_t)(32 + srow) * SEQQ + kt + scol,    &Vs[2048 + wave * 512]);
    __syncthreads();   // drain global_load_lds + visibility

    // K fragments ([key=l15][d=quad*8+j]) — shared by all 4 subtile-computes
    short8 kf[4][2];
#pragma unroll
    for (int ni = 0; ni < 4; ++ni)
#pragma unroll
      for (int ks = 0; ks < 2; ++ks)
        kf[ni][ks] = *(const short8*)&Ks[(ni * 16 + l15) * 64 +
                                         ((ks * 32 + quad * 8) ^ ((l15 & 7) * 8))];
    // V fragments ([d=l15][key=quad*8+j]) — shared by all 4 PV computes
    short8 vf[2][4];
#pragma unroll
    for (int kc = 0; kc < 2; ++kc)
#pragma unroll
      for (int di = 0; di < 4; ++di)
        vf[kc][di] = *(const short8*)&Vs[(di * 16 + l15) * 64 +
                                         ((kc * 32 + quad * 8) ^ ((l15 & 7) * 8))];

#pragma unroll
    for (int mi = 0; mi < 2; ++mi) {     // group A subtiles
      const int qm = qwA + mi * 16;      // wave-uniform
      if (kt <= qm + 15) {
        floatx4 st[4];
#pragma unroll
        for (int ni = 0; ni < 4; ++ni) {
          floatx4 s = (floatx4){0.f, 0.f, 0.f, 0.f};
          s = mfma16(kf[ni][0], qfA[mi][0], s);
          s = mfma16(kf[ni][1], qfA[mi][1], s);
          st[ni] = s;
        }
        if (kt + 63 > qm) {   // diagonal: mask key > q
          const int qg = qm + l15;
#pragma unroll
          for (int ni = 0; ni < 4; ++ni) {
            const int kg = kt + ni * 16 + quad * 4;
#pragma unroll
            for (int r = 0; r < 4; ++r)
              if (kg + r > qg) st[ni][r] = -1e30f;
          }
        }
        softmax_pv_T(st, lpA[mi], accA[mi], psw, vf, quad, l15, mi);
      }
    }
#pragma unroll
    for (int mi = 0; mi < 2; ++mi) {     // group B subtiles
      const int qm = qwB + mi * 16;
      if (kt <= qm + 15) {
        floatx4 st[4];
#pragma unroll
        for (int ni = 0; ni < 4; ++ni) {
          floatx4 s = (floatx4){0.f, 0.f, 0.f, 0.f};
          s = mfma16(kf[ni][0], qfB[mi][0], s);
          s = mfma16(kf[ni][1], qfB[mi][1], s);
          st[ni] = s;
        }
        if (kt + 63 > qm) {
          const int qg = qm + l15;
#pragma unroll
          for (int ni = 0; ni < 4; ++ni) {
            const int kg = kt + ni * 16 + quad * 4;
#pragma unroll
            for (int r = 0; r < 4; ++r)
              if (kg + r > qg) st[ni][r] = -1e30f;
          }
        }
        softmax_pv_T(st, lpB[mi], accB[mi], psw, vf, quad, l15, mi);
      }
    }
  }

  // l reduce across the 4 quad groups -> every lane holds l(q=l15) per subtile
#pragma unroll
  for (int mi = 0; mi < 2; ++mi) {
    lpA[mi] += __shfl_xor(lpA[mi], 16); lpA[mi] += __shfl_xor(lpA[mi], 32);
    lpB[mi] += __shfl_xor(lpB[mi], 16); lpB[mi] += __shfl_xor(lpB[mi], 32);
  }

  // epilogue: O rows q=quad*4+r, cols d=di*16+l15; l for row via shfl
#pragma unroll
  for (int mi = 0; mi < 2; ++mi) {
    u16* orow = O + (size_t)(b * SEQQ + qwA + mi * 16 + quad * 4) * D_MODEL + h * HDIM + l15;
#pragma unroll
    for (int r = 0; r < 4; ++r) {
      const float inv = 1.0f / __shfl(lpA[mi], quad * 4 + r, 16);
#pragma unroll
      for (int di = 0; di < 4; ++di)
        orow[(size_t)r * D_MODEL + di * 16] = f2bf(accA[mi][di][r] * inv);
    }
  }
#pragma unroll
  for (int mi = 0; mi < 2; ++mi) {
    u16* orow = O + (size_t)(b * SEQQ + qwB + mi * 16 + quad * 4) * D_MODEL + h * HDIM + l15;
#pragma unroll
    for (int r = 0; r < 4; ++r) {
      const float inv = 1.0f / __shfl(lpB[mi], quad * 4 + r, 16);
#pragma unroll
      for (int di = 0; di < 4; ++di)
        orow[(size_t)r * D_MODEL + di * 16] = f2bf(accB[mi][di][r] * inv);
    }
  }
}

// ---------------------------------------------------------------- launch
extern "C" void kernel_launch(void* const* d_in, const int* in_sizes, int n_in,
                              void* d_out, int out_size, void* d_ws, size_t ws_size,
                              hipStream_t stream) {
  const float* X  = (const float*)d_in[0];
  const float* Wq = (const float*)d_in[1];
  const float* Wk = (const float*)d_in[2];
  const float* Wv = (const float*)d_in[3];
  const float* Wo = (const float*)d_in[4];
  const float* bo = (const float*)d_in[5];
  float* out = (float*)d_out;

  u16* ws = (u16*)d_ws;
  const size_t NE = (size_t)MTOT * D_MODEL;    // 8,388,608
  u16* Xb  = ws;
  u16* Qb  = Xb + NE;
  u16* Kb  = Qb + NE;
  u16* Vb  = Kb + NE;
  u16* Vt  = Vb + NE;
  u16* Cb  = Vt + NE;
  u16* Wqb = Cb + NE;
  u16* Wkb = Wqb + (size_t)D_MODEL * D_MODEL;
  u16* Wvb = Wkb + (size_t)D_MODEL * D_MODEL;
  u16* Wob = Wvb + (size_t)D_MODEL * D_MODEL;

  const float SCL2E = 0.18033688f;   // (1/sqrt(64)) * log2(e), folded into Q

  // 1. all casts in one launch
  k_cast_all<<<12288, 256, 0, stream>>>(X, Wq, Wk, Wv, Wo, Xb, Wqb, Wkb, Wvb, Wob);

  // 2. fused QKV projections (Q pre-scaled by SCL2E)
  k_gemm_bt<<<dim3(D_MODEL / 128, MTOT / 128, 3), 256, 0, stream>>>(
      Xb, Wqb, Wkb, Wvb, Qb, Kb, Vb, nullptr, MTOT, D_MODEL, D_MODEL, 0, SCL2E);

  // 3. V -> [bh][64][2048]
  k_transpose_v<<<dim3(SEQQ / 64, NBATCH * NHEAD), 256, 0, stream>>>(Vb, Vt);

  // 4. causal flash attention, paired 128-row q-tiles -> Cb [8192][1024]
  k_attn<<<dim3(8, NBATCH * NHEAD), 256, 0, stream>>>(Qb, Kb, Vt, Cb);

  // 5. output projection + bias, f32 out
  k_gemm_bt<<<dim3(D_MODEL / 128, MTOT / 128, 1), 256, 0, stream>>>(
      Cb, Wob, Wob, Wob, out, out, out, bo, MTOT, D_MODEL, D_MODEL, 1, 1.0f);
}

// Round 6
// 283.142 us; speedup vs baseline: 1.1105x; 1.1105x over previous
//
#include <hip/hip_runtime.h>
#include <cstdint>
#include <cstddef>

// Problem constants (MultiHeadAttention: B=4, T=2048, d_model=1024, H=16, hd=64)
#define D_MODEL 1024
#define SEQQ    2048
#define NBATCH  4
#define NHEAD   16
#define HDIM    64
#define MTOT    (NBATCH * SEQQ)   // 8192 rows

typedef __attribute__((ext_vector_type(8))) short short8;   // 8 x bf16 (4 VGPRs) — MFMA A/B frag
typedef __attribute__((ext_vector_type(4))) float floatx4;  // MFMA C/D frag
typedef unsigned short u16;                                  // bf16 bits

__device__ __forceinline__ u16 f2bf(float f) {
  union { float f; uint32_t u; } a; a.f = f;
  uint32_t u = a.u;
  u += 0x7fffu + ((u >> 16) & 1u);   // RN-even
  return (u16)(u >> 16);
}

__device__ __forceinline__ floatx4 mfma16(short8 a, short8 b, floatx4 c) {
  return __builtin_amdgcn_mfma_f32_16x16x32_bf16(a, b, c, 0, 0, 0);
}

// async global->LDS, 16B per lane. LDS dest = wave-uniform base + lane*16.
__device__ __forceinline__ void load_lds16(const void* g, void* l) {
  __builtin_amdgcn_global_load_lds(
      (const __attribute__((address_space(1))) uint32_t*)g,
      (__attribute__((address_space(3))) uint32_t*)l, 16, 0, 0);
}

// ---------------------------------------------------------------- fused casts f32->bf16
// blocks [0, 8192): X. blocks [8192, 12288): weights, 1024 blocks each.
__global__ __launch_bounds__(256) void k_cast_all(
    const float* __restrict__ X, const float* __restrict__ w0,
    const float* __restrict__ w1, const float* __restrict__ w2,
    const float* __restrict__ w3,
    u16* __restrict__ xb, u16* __restrict__ y0, u16* __restrict__ y1,
    u16* __restrict__ y2, u16* __restrict__ y3) {
  const int bx = blockIdx.x;
  const float* src; u16* dst; int i;
  if (bx < 8192) {
    src = X; dst = xb; i = (bx * 256 + threadIdx.x) * 4;
  } else {
    const int w = (bx - 8192) >> 10;
    src = (w == 0) ? w0 : (w == 1) ? w1 : (w == 2) ? w2 : w3;
    dst = (w == 0) ? y0 : (w == 1) ? y1 : (w == 2) ? y2 : y3;
    i = (((bx - 8192) & 1023) * 256 + threadIdx.x) * 4;
  }
  float4 v = *(const float4*)(src + i);
  ushort4 o;
  o.x = f2bf(v.x); o.y = f2bf(v.y); o.z = f2bf(v.z); o.w = f2bf(v.w);
  *(ushort4*)(dst + i) = o;
}

// ---------------------------------------------------------------- GEMM  C = A @ B^T (+bias)
// ascaleQ: extra scale on the z==0 output (folds 1/sqrt(hd)*log2e into Q).
// z==2 (V projection): epilogue writes TRANSPOSED into Vt [bh][64][2048]
// (4 acc regs = 4 consecutive t -> one packed 8B store per 16x16 tile).
__global__ __launch_bounds__(256) void k_gemm_bt(
    const u16* __restrict__ A,
    const u16* __restrict__ B0, const u16* __restrict__ B1, const u16* __restrict__ B2,
    void* __restrict__ C0, void* __restrict__ C1, u16* __restrict__ VtOut,
    const float* __restrict__ bias, int M, int N, int K, int f32out, float ascaleQ) {
  __shared__ __align__(16) u16 As[128 * 64];
  __shared__ __align__(16) u16 Bs[128 * 64];
  const int tid = threadIdx.x;
  const int lane = tid & 63, wave = tid >> 6;
  const int quad = lane >> 4, l15 = lane & 15;
  const int m0 = blockIdx.y * 128, n0 = blockIdx.x * 128;
  const int wr = wave >> 1, wc = wave & 1;
  const u16* Bm = (blockIdx.z == 0) ? B0 : (blockIdx.z == 1 ? B1 : B2);
  void* Cm = (blockIdx.z == 0) ? C0 : C1;
  const float ascale = (blockIdx.z == 0) ? ascaleQ : 1.0f;

  floatx4 acc[4][4];
#pragma unroll
  for (int i = 0; i < 4; ++i)
#pragma unroll
    for (int j = 0; j < 4; ++j) acc[i][j] = (floatx4){0.f, 0.f, 0.f, 0.f};

  const int srow = tid >> 3;                       // 0..31
  const int scolx = ((tid & 7) * 8) ^ ((srow & 7) * 8);  // swizzled source column
  const u16* Ag = A + (size_t)(m0 + srow) * K + scolx;
  const u16* Bg = Bm + (size_t)(n0 + srow) * K + scolx;

  for (int kt = 0; kt < K; kt += 64) {
    __syncthreads();
#pragma unroll
    for (int p = 0; p < 4; ++p) {
      load_lds16(Ag + (size_t)(p * 32) * K + kt, &As[p * 2048 + wave * 512]);
      load_lds16(Bg + (size_t)(p * 32) * K + kt, &Bs[p * 2048 + wave * 512]);
    }
    __syncthreads();

    short8 af[2][4], bfg[2][4];
#pragma unroll
    for (int ks = 0; ks < 2; ++ks) {
      const int kkx = (ks * 32 + quad * 8) ^ ((l15 & 7) * 8);
#pragma unroll
      for (int i = 0; i < 4; ++i) {
        af[ks][i]  = *(const short8*)&As[(wr * 64 + i * 16 + l15) * 64 + kkx];
        bfg[ks][i] = *(const short8*)&Bs[(wc * 64 + i * 16 + l15) * 64 + kkx];
      }
    }
#pragma unroll
    for (int ks = 0; ks < 2; ++ks)
#pragma unroll
      for (int mi = 0; mi < 4; ++mi)
#pragma unroll
        for (int ni = 0; ni < 4; ++ni)
          acc[mi][ni] = mfma16(af[ks][mi], bfg[ks][ni], acc[mi][ni]);
  }

  // Epilogue. C/D layout: col = lane&15, row = quad*4 + reg (m89-verified).
  if (blockIdx.z == 2) {
    // transposed V write: Vt[(b*16+h)*64 + d][t], 4 regs = t..t+3 contiguous
#pragma unroll
    for (int mi = 0; mi < 4; ++mi) {
#pragma unroll
      for (int ni = 0; ni < 4; ++ni) {
        const int row = m0 + wr * 64 + mi * 16 + quad * 4;   // token
        const int col = n0 + wc * 64 + ni * 16 + l15;        // channel
        const int b = row >> 11, t = row & 2047;
        const int h = col >> 6, d = col & 63;
        ushort4 pk;
        pk.x = f2bf(acc[mi][ni][0]); pk.y = f2bf(acc[mi][ni][1]);
        pk.z = f2bf(acc[mi][ni][2]); pk.w = f2bf(acc[mi][ni][3]);
        *(ushort4*)(VtOut + (((size_t)(b * 16 + h) * 64 + d) * SEQQ + t)) = pk;
      }
    }
    return;
  }
#pragma unroll
  for (int mi = 0; mi < 4; ++mi) {
#pragma unroll
    for (int ni = 0; ni < 4; ++ni) {
      const int row = m0 + wr * 64 + mi * 16 + quad * 4;
      const int col = n0 + wc * 64 + ni * 16 + l15;
      const float bv = bias ? bias[col] : 0.f;
#pragma unroll
      for (int r = 0; r < 4; ++r) {
        const float v = acc[mi][ni][r] * ascale + bv;
        if (f32out) ((float*)Cm)[(size_t)(row + r) * N + col] = v;
        else        ((u16*)Cm)[(size_t)(row + r) * N + col] = f2bf(v);
      }
    }
  }
}

// ---------------------------------------------------------------- flash attention
// ROUND-4 STRUCTURE (proven): paired q-tiles (p, 31-p), 64-row granularity,
// 4 waves x 16 q-rows, grid 16x64=1024 blocks (latency-hiding occupancy —
// the 128-row variant halved occupancy and regressed, r5).
// S^T = K·Q^T (lane = one query), static-max softmax, per-lane l, zero
// shuffles in loop. New vs r4: v_perm_b32 RTZ bf16 packing (2 vals/instr)
// and ONE lgkmcnt wait per iter — B's QK^T MFMAs fill A's pack latency;
// P_A and P_B live in separate per-wave LDS regions.
__device__ __forceinline__ void softmax_pack(
    floatx4 (&st)[4], float& lp, u16* psw, int quad, int l15) {
#pragma unroll
  for (int ni = 0; ni < 4; ++ni) {
    const float p0 = __builtin_amdgcn_exp2f(st[ni][0]);
    const float p1 = __builtin_amdgcn_exp2f(st[ni][1]);
    const float p2 = __builtin_amdgcn_exp2f(st[ni][2]);
    const float p3 = __builtin_amdgcn_exp2f(st[ni][3]);
    lp += (p0 + p1) + (p2 + p3);
    uint2 pk;
    pk.x = __builtin_amdgcn_perm(__float_as_uint(p1), __float_as_uint(p0), 0x07060302u);
    pk.y = __builtin_amdgcn_perm(__float_as_uint(p3), __float_as_uint(p2), 0x07060302u);
    *(uint2*)&psw[l15 * 72 + ni * 16 + quad * 4] = pk;   // [q][key], 8B store
  }
}

__device__ __forceinline__ void pv_mfma(
    floatx4 (&acc)[4], const u16* psw, const short8 (&vf)[2][4], int quad, int l15) {
#pragma unroll
  for (int kc = 0; kc < 2; ++kc) {
    const short8 pf = *(const short8*)&psw[l15 * 72 + kc * 32 + quad * 8];
#pragma unroll
    for (int di = 0; di < 4; ++di)
      acc[di] = mfma16(pf, vf[kc][di], acc[di]);
  }
}

__global__ __launch_bounds__(256) void k_attn(
    const u16* __restrict__ Q, const u16* __restrict__ Kg,
    const u16* __restrict__ Vt, u16* __restrict__ O) {
  __shared__ __align__(16) u16 Ks[64 * 64];
  __shared__ __align__(16) u16 Vs[64 * 64];
  __shared__ __align__(16) u16 Ps[4][2][16 * 72];  // [wave][subtile A/B]
  const int tid = threadIdx.x, lane = tid & 63, wave = tid >> 6;
  const int quad = lane >> 4, l15 = lane & 15;
  const int bh = blockIdx.y, b = bh >> 4, h = bh & 15;
  const int p = blockIdx.x;                  // pair index 0..15
  const int qwA = 64 * p + wave * 16;
  const int qwB = SEQQ - 64 * (p + 1) + wave * 16;
  const int nT = 32 - p;                     // k-tiles for B (>= A's p+1)

  const u16* kbase = Kg + (size_t)(b * SEQQ) * D_MODEL + h * HDIM;
  const u16* vbase = Vt + (size_t)bh * (HDIM * SEQQ);

  // Q fragments ([idx=l15][k=quad*8+j]); Q pre-scaled by 1/sqrt(hd)*log2e.
  short8 qfA[2], qfB[2];
  {
    const u16* qa = Q + (size_t)(b * SEQQ + qwA + l15) * D_MODEL + h * HDIM;
    const u16* qb = Q + (size_t)(b * SEQQ + qwB + l15) * D_MODEL + h * HDIM;
#pragma unroll
    for (int ks = 0; ks < 2; ++ks) {
      qfA[ks] = *(const short8*)(qa + ks * 32 + quad * 8);
      qfB[ks] = *(const short8*)(qb + ks * 32 + quad * 8);
    }
  }

  floatx4 accA[4], accB[4];
  float lAp = 0.f, lBp = 0.f;     // per-lane partial softmax denominators
#pragma unroll
  for (int i = 0; i < 4; ++i) {
    accA[i] = (floatx4){0.f, 0.f, 0.f, 0.f};
    accB[i] = (floatx4){0.f, 0.f, 0.f, 0.f};
  }

  const int srow = tid >> 3;                            // 0..31
  const int scol = ((tid & 7) * 8) ^ ((srow & 7) * 8);  // swizzled col 0..63
  u16* pswA = &Ps[wave][0][0];
  u16* pswB = &Ps[wave][1][0];

  for (int t = 0; t < nT; ++t) {
    const int kt = t * 64;
    __syncthreads();   // protect previous iter's LDS reads
    load_lds16(kbase + (size_t)(kt + srow) * D_MODEL + scol,      &Ks[wave * 512]);
    load_lds16(kbase + (size_t)(kt + 32 + srow) * D_MODEL + scol, &Ks[2048 + wave * 512]);
    load_lds16(vbase + (size_t)srow * SEQQ + kt + scol,           &Vs[wave * 512]);
    load_lds16(vbase + (size_t)(32 + srow) * SEQQ + kt + scol,    &Vs[2048 + wave * 512]);
    __syncthreads();   // drain global_load_lds + visibility

    // K fragments ([key=l15][d=quad*8+j]), shared by both q-tiles
    short8 kf[4][2];
#pragma unroll
    for (int ni = 0; ni < 4; ++ni)
#pragma unroll
      for (int ks = 0; ks < 2; ++ks)
        kf[ni][ks] = *(const short8*)&Ks[(ni * 16 + l15) * 64 +
                                         ((ks * 32 + quad * 8) ^ ((l15 & 7) * 8))];
    // V fragments ([d=l15][key=quad*8+j]), shared by both q-tiles
    short8 vf[2][4];
#pragma unroll
    for (int kc = 0; kc < 2; ++kc)
#pragma unroll
      for (int di = 0; di < 4; ++di)
        vf[kc][di] = *(const short8*)&Vs[(di * 16 + l15) * 64 +
                                         ((kc * 32 + quad * 8) ^ ((l15 & 7) * 8))];

    const bool doA = (t <= p);   // block-uniform
    if (doA) {
      floatx4 st[4];   // S^T: row=key (quad*4+r, tile ni), col=q (l15)
#pragma unroll
      for (int ni = 0; ni < 4; ++ni) {
        floatx4 s = (floatx4){0.f, 0.f, 0.f, 0.f};
        s = mfma16(kf[ni][0], qfA[0], s);
        s = mfma16(kf[ni][1], qfA[1], s);
        st[ni] = s;
      }
      if (t == p) {   // diagonal tile of A: mask key > q
        const int qg = qwA + l15;
#pragma unroll
        for (int ni = 0; ni < 4; ++ni) {
          const int kg = kt + ni * 16 + quad * 4;
#pragma unroll
          for (int r = 0; r < 4; ++r)
            if (kg + r > qg) st[ni][r] = -1e30f;
        }
      }
      softmax_pack(st, lAp, pswA, quad, l15);
    }
    {
      floatx4 st[4];
#pragma unroll
      for (int ni = 0; ni < 4; ++ni) {
        floatx4 s = (floatx4){0.f, 0.f, 0.f, 0.f};
        s = mfma16(kf[ni][0], qfB[0], s);   // fills pswA write latency
        s = mfma16(kf[ni][1], qfB[1], s);
        st[ni] = s;
      }
      if (t == nT - 1) {   // diagonal tile of B
        const int qg = qwB + l15;
#pragma unroll
        for (int ni = 0; ni < 4; ++ni) {
          const int kg = kt + ni * 16 + quad * 4;
#pragma unroll
          for (int r = 0; r < 4; ++r)
            if (kg + r > qg) st[ni][r] = -1e30f;
        }
      }
      softmax_pack(st, lBp, pswB, quad, l15);
    }
    asm volatile("s_waitcnt lgkmcnt(0)" ::: "memory");  // single wait per iter
    if (doA) pv_mfma(accA, pswA, vf, quad, l15);
    pv_mfma(accB, pswB, vf, quad, l15);
  }

  // l reduce: across the 4 quad groups (same l15) -> every lane holds l(q=l15)
  lAp += __shfl_xor(lAp, 16); lAp += __shfl_xor(lAp, 32);
  lBp += __shfl_xor(lBp, 16); lBp += __shfl_xor(lBp, 32);

  // epilogue: O rows q=quad*4+r, cols d=di*16+l15; l for row via shfl
  {
    u16* orow = O + (size_t)(b * SEQQ + qwA + quad * 4) * D_MODEL + h * HDIM + l15;
#pragma unroll
    for (int r = 0; r < 4; ++r) {
      const float inv = 1.0f / __shfl(lAp, quad * 4 + r, 16);
#pragma unroll
      for (int di = 0; di < 4; ++di)
        orow[(size_t)r * D_MODEL + di * 16] = f2bf(accA[di][r] * inv);
    }
  }
  {
    u16* orow = O + (size_t)(b * SEQQ + qwB + quad * 4) * D_MODEL + h * HDIM + l15;
#pragma unroll
    for (int r = 0; r < 4; ++r) {
      const float inv = 1.0f / __shfl(lBp, quad * 4 + r, 16);
#pragma unroll
      for (int di = 0; di < 4; ++di)
        orow[(size_t)r * D_MODEL + di * 16] = f2bf(accB[di][r] * inv);
    }
  }
}

// ---------------------------------------------------------------- launch
extern "C" void kernel_launch(void* const* d_in, const int* in_sizes, int n_in,
                              void* d_out, int out_size, void* d_ws, size_t ws_size,
                              hipStream_t stream) {
  const float* X  = (const float*)d_in[0];
  const float* Wq = (const float*)d_in[1];
  const float* Wk = (const float*)d_in[2];
  const float* Wv = (const float*)d_in[3];
  const float* Wo = (const float*)d_in[4];
  const float* bo = (const float*)d_in[5];
  float* out = (float*)d_out;

  u16* ws = (u16*)d_ws;
  const size_t NE = (size_t)MTOT * D_MODEL;    // 8,388,608
  u16* Xb  = ws;
  u16* Qb  = Xb + NE;
  u16* Kb  = Qb + NE;
  u16* Vt  = Kb + NE;          // V projection written directly transposed
  u16* Cb  = Vt + NE;
  u16* Wqb = Cb + NE;
  u16* Wkb = Wqb + (size_t)D_MODEL * D_MODEL;
  u16* Wvb = Wkb + (size_t)D_MODEL * D_MODEL;
  u16* Wob = Wvb + (size_t)D_MODEL * D_MODEL;

  const float SCL2E = 0.18033688f;   // (1/sqrt(64)) * log2(e), folded into Q

  // 1. all casts in one launch
  k_cast_all<<<12288, 256, 0, stream>>>(X, Wq, Wk, Wv, Wo, Xb, Wqb, Wkb, Wvb, Wob);

  // 2. fused QKV projections (Q pre-scaled; V written transposed into Vt)
  k_gemm_bt<<<dim3(D_MODEL / 128, MTOT / 128, 3), 256, 0, stream>>>(
      Xb, Wqb, Wkb, Wvb, Qb, Kb, Vt, nullptr, MTOT, D_MODEL, D_MODEL, 0, SCL2E);

  // 3. causal flash attention, paired 64-row q-tiles -> Cb [8192][1024]
  k_attn<<<dim3(16, NBATCH * NHEAD), 256, 0, stream>>>(Qb, Kb, Vt, Cb);

  // 4. output projection + bias, f32 out
  k_gemm_bt<<<dim3(D_MODEL / 128, MTOT / 128, 1), 256, 0, stream>>>(
      Cb, Wob, Wob, Wob, out, out, nullptr, bo, MTOT, D_MODEL, D_MODEL, 1, 1.0f);
}

// Round 7
// 282.817 us; speedup vs baseline: 1.1118x; 1.0011x over previous
//
#include <hip/hip_runtime.h>
#include <cstdint>
#include <cstddef>

// Problem constants (MultiHeadAttention: B=4, T=2048, d_model=1024, H=16, hd=64)
#define D_MODEL 1024
#define SEQQ    2048
#define NBATCH  4
#define NHEAD   16
#define HDIM    64
#define MTOT    (NBATCH * SEQQ)   // 8192 rows

typedef __attribute__((ext_vector_type(8))) short short8;   // 8 x bf16 (4 VGPRs) — MFMA A/B frag
typedef __attribute__((ext_vector_type(4))) float floatx4;  // MFMA C/D frag
typedef unsigned short u16;                                  // bf16 bits

__device__ __forceinline__ u16 f2bf(float f) {
  union { float f; uint32_t u; } a; a.f = f;
  uint32_t u = a.u;
  u += 0x7fffu + ((u >> 16) & 1u);   // RN-even
  return (u16)(u >> 16);
}

__device__ __forceinline__ floatx4 mfma16(short8 a, short8 b, floatx4 c) {
  return __builtin_amdgcn_mfma_f32_16x16x32_bf16(a, b, c, 0, 0, 0);
}

// async global->LDS, 16B per lane. LDS dest = wave-uniform base + lane*16.
__device__ __forceinline__ void load_lds16(const void* g, void* l) {
  __builtin_amdgcn_global_load_lds(
      (const __attribute__((address_space(1))) uint32_t*)g,
      (__attribute__((address_space(3))) uint32_t*)l, 16, 0, 0);
}

// ---------------------------------------------------------------- fused casts f32->bf16
// blocks [0, 8192): X. blocks [8192, 12288): weights, 1024 blocks each.
__global__ __launch_bounds__(256) void k_cast_all(
    const float* __restrict__ X, const float* __restrict__ w0,
    const float* __restrict__ w1, const float* __restrict__ w2,
    const float* __restrict__ w3,
    u16* __restrict__ xb, u16* __restrict__ y0, u16* __restrict__ y1,
    u16* __restrict__ y2, u16* __restrict__ y3) {
  const int bx = blockIdx.x;
  const float* src; u16* dst; int i;
  if (bx < 8192) {
    src = X; dst = xb; i = (bx * 256 + threadIdx.x) * 4;
  } else {
    const int w = (bx - 8192) >> 10;
    src = (w == 0) ? w0 : (w == 1) ? w1 : (w == 2) ? w2 : w3;
    dst = (w == 0) ? y0 : (w == 1) ? y1 : (w == 2) ? y2 : y3;
    i = (((bx - 8192) & 1023) * 256 + threadIdx.x) * 4;
  }
  float4 v = *(const float4*)(src + i);
  ushort4 o;
  o.x = f2bf(v.x); o.y = f2bf(v.y); o.z = f2bf(v.z); o.w = f2bf(v.w);
  *(ushort4*)(dst + i) = o;
}

// ---------------------------------------------------------------- GEMM  C = A @ B^T (+bias)
// ascaleQ: extra scale on the z==0 output (folds 1/sqrt(hd)*log2e into Q).
// z==2 (V projection): epilogue writes TRANSPOSED into Vt [bh][64][2048].
__global__ __launch_bounds__(256) void k_gemm_bt(
    const u16* __restrict__ A,
    const u16* __restrict__ B0, const u16* __restrict__ B1, const u16* __restrict__ B2,
    void* __restrict__ C0, void* __restrict__ C1, u16* __restrict__ VtOut,
    const float* __restrict__ bias, int M, int N, int K, int f32out, float ascaleQ) {
  __shared__ __align__(16) u16 As[128 * 64];
  __shared__ __align__(16) u16 Bs[128 * 64];
  const int tid = threadIdx.x;
  const int lane = tid & 63, wave = tid >> 6;
  const int quad = lane >> 4, l15 = lane & 15;
  const int m0 = blockIdx.y * 128, n0 = blockIdx.x * 128;
  const int wr = wave >> 1, wc = wave & 1;
  const u16* Bm = (blockIdx.z == 0) ? B0 : (blockIdx.z == 1 ? B1 : B2);
  void* Cm = (blockIdx.z == 0) ? C0 : C1;
  const float ascale = (blockIdx.z == 0) ? ascaleQ : 1.0f;

  floatx4 acc[4][4];
#pragma unroll
  for (int i = 0; i < 4; ++i)
#pragma unroll
    for (int j = 0; j < 4; ++j) acc[i][j] = (floatx4){0.f, 0.f, 0.f, 0.f};

  const int srow = tid >> 3;                       // 0..31
  const int scolx = ((tid & 7) * 8) ^ ((srow & 7) * 8);  // swizzled source column
  const u16* Ag = A + (size_t)(m0 + srow) * K + scolx;
  const u16* Bg = Bm + (size_t)(n0 + srow) * K + scolx;

  for (int kt = 0; kt < K; kt += 64) {
    __syncthreads();
#pragma unroll
    for (int p = 0; p < 4; ++p) {
      load_lds16(Ag + (size_t)(p * 32) * K + kt, &As[p * 2048 + wave * 512]);
      load_lds16(Bg + (size_t)(p * 32) * K + kt, &Bs[p * 2048 + wave * 512]);
    }
    __syncthreads();

    short8 af[2][4], bfg[2][4];
#pragma unroll
    for (int ks = 0; ks < 2; ++ks) {
      const int kkx = (ks * 32 + quad * 8) ^ ((l15 & 7) * 8);
#pragma unroll
      for (int i = 0; i < 4; ++i) {
        af[ks][i]  = *(const short8*)&As[(wr * 64 + i * 16 + l15) * 64 + kkx];
        bfg[ks][i] = *(const short8*)&Bs[(wc * 64 + i * 16 + l15) * 64 + kkx];
      }
    }
#pragma unroll
    for (int ks = 0; ks < 2; ++ks)
#pragma unroll
      for (int mi = 0; mi < 4; ++mi)
#pragma unroll
        for (int ni = 0; ni < 4; ++ni)
          acc[mi][ni] = mfma16(af[ks][mi], bfg[ks][ni], acc[mi][ni]);
  }

  // Epilogue. C/D layout: col = lane&15, row = quad*4 + reg (m89-verified).
  if (blockIdx.z == 2) {
    // transposed V write: Vt[(b*16+h)*64 + d][t], 4 regs = t..t+3 contiguous
#pragma unroll
    for (int mi = 0; mi < 4; ++mi) {
#pragma unroll
      for (int ni = 0; ni < 4; ++ni) {
        const int row = m0 + wr * 64 + mi * 16 + quad * 4;   // token
        const int col = n0 + wc * 64 + ni * 16 + l15;        // channel
        const int b = row >> 11, t = row & 2047;
        const int h = col >> 6, d = col & 63;
        ushort4 pk;
        pk.x = f2bf(acc[mi][ni][0]); pk.y = f2bf(acc[mi][ni][1]);
        pk.z = f2bf(acc[mi][ni][2]); pk.w = f2bf(acc[mi][ni][3]);
        *(ushort4*)(VtOut + (((size_t)(b * 16 + h) * 64 + d) * SEQQ + t)) = pk;
      }
    }
    return;
  }
#pragma unroll
  for (int mi = 0; mi < 4; ++mi) {
#pragma unroll
    for (int ni = 0; ni < 4; ++ni) {
      const int row = m0 + wr * 64 + mi * 16 + quad * 4;
      const int col = n0 + wc * 64 + ni * 16 + l15;
      const float bv = bias ? bias[col] : 0.f;
#pragma unroll
      for (int r = 0; r < 4; ++r) {
        const float v = acc[mi][ni][r] * ascale + bv;
        if (f32out) ((float*)Cm)[(size_t)(row + r) * N + col] = v;
        else        ((u16*)Cm)[(size_t)(row + r) * N + col] = f2bf(v);
      }
    }
  }
}

// ---------------------------------------------------------------- flash attention
// r4/r6 structure (paired q-tiles (p,31-p), 64-row granularity, 4 waves x 16 q)
// + DOUBLE-BUFFERED K/V staging with ONE barrier per iteration: stage(t+1)
// issued right after the barrier, overlapping iter t's whole compute body —
// removes the staging drain from the per-iter critical path (attn is
// serial-latency bound: ~918 ns/block-iter at only ~1.4x overlap, r6 PMC).
// Safety: buf[(t+1)&1]'s readers finished before the iter-t barrier (compiler
// drains lgkm+vmcnt before s_barrier, m97-verified); the iter-t+1 barrier
// drains stage(t+1) before its first read. Ps is per-wave (no x-wave hazard).
__device__ __forceinline__ void softmax_pack(
    floatx4 (&st)[4], float& lp, u16* psw, int quad, int l15) {
#pragma unroll
  for (int ni = 0; ni < 4; ++ni) {
    const float p0 = __builtin_amdgcn_exp2f(st[ni][0]);
    const float p1 = __builtin_amdgcn_exp2f(st[ni][1]);
    const float p2 = __builtin_amdgcn_exp2f(st[ni][2]);
    const float p3 = __builtin_amdgcn_exp2f(st[ni][3]);
    lp += (p0 + p1) + (p2 + p3);
    uint2 pk;
    pk.x = __builtin_amdgcn_perm(__float_as_uint(p1), __float_as_uint(p0), 0x07060302u);
    pk.y = __builtin_amdgcn_perm(__float_as_uint(p3), __float_as_uint(p2), 0x07060302u);
    *(uint2*)&psw[l15 * 72 + ni * 16 + quad * 4] = pk;   // [q][key], 8B store
  }
}

__device__ __forceinline__ void pv_mfma(
    floatx4 (&acc)[4], const u16* psw, const short8 (&vf)[2][4], int quad, int l15) {
#pragma unroll
  for (int kc = 0; kc < 2; ++kc) {
    const short8 pf = *(const short8*)&psw[l15 * 72 + kc * 32 + quad * 8];
#pragma unroll
    for (int di = 0; di < 4; ++di)
      acc[di] = mfma16(pf, vf[kc][di], acc[di]);
  }
}

__global__ __launch_bounds__(256) void k_attn(
    const u16* __restrict__ Q, const u16* __restrict__ Kg,
    const u16* __restrict__ Vt, u16* __restrict__ O) {
  __shared__ __align__(16) u16 Ks[2][64 * 64];
  __shared__ __align__(16) u16 Vs[2][64 * 64];
  __shared__ __align__(16) u16 Ps[4][2][16 * 72];  // [wave][subtile A/B]
  const int tid = threadIdx.x, lane = tid & 63, wave = tid >> 6;
  const int quad = lane >> 4, l15 = lane & 15;
  const int bh = blockIdx.y, b = bh >> 4, h = bh & 15;
  const int p = blockIdx.x;                  // pair index 0..15
  const int qwA = 64 * p + wave * 16;
  const int qwB = SEQQ - 64 * (p + 1) + wave * 16;
  const int nT = 32 - p;                     // k-tiles for B (>= A's p+1)

  const u16* kbase = Kg + (size_t)(b * SEQQ) * D_MODEL + h * HDIM;
  const u16* vbase = Vt + (size_t)bh * (HDIM * SEQQ);

  const int srow = tid >> 3;                            // 0..31
  const int scol = ((tid & 7) * 8) ^ ((srow & 7) * 8);  // swizzled col 0..63

  // issue first staging before anything else
  {
    load_lds16(kbase + (size_t)srow * D_MODEL + scol,        &Ks[0][wave * 512]);
    load_lds16(kbase + (size_t)(32 + srow) * D_MODEL + scol, &Ks[0][2048 + wave * 512]);
    load_lds16(vbase + (size_t)srow * SEQQ + scol,           &Vs[0][wave * 512]);
    load_lds16(vbase + (size_t)(32 + srow) * SEQQ + scol,    &Vs[0][2048 + wave * 512]);
  }

  // Q fragments ([idx=l15][k=quad*8+j]); Q pre-scaled by 1/sqrt(hd)*log2e.
  short8 qfA[2], qfB[2];
  {
    const u16* qa = Q + (size_t)(b * SEQQ + qwA + l15) * D_MODEL + h * HDIM;
    const u16* qb = Q + (size_t)(b * SEQQ + qwB + l15) * D_MODEL + h * HDIM;
#pragma unroll
    for (int ks = 0; ks < 2; ++ks) {
      qfA[ks] = *(const short8*)(qa + ks * 32 + quad * 8);
      qfB[ks] = *(const short8*)(qb + ks * 32 + quad * 8);
    }
  }

  floatx4 accA[4], accB[4];
  float lAp = 0.f, lBp = 0.f;     // per-lane partial softmax denominators
#pragma unroll
  for (int i = 0; i < 4; ++i) {
    accA[i] = (floatx4){0.f, 0.f, 0.f, 0.f};
    accB[i] = (floatx4){0.f, 0.f, 0.f, 0.f};
  }

  u16* pswA = &Ps[wave][0][0];
  u16* pswB = &Ps[wave][1][0];

  for (int t = 0; t < nT; ++t) {
    const int cur = t & 1;
    __syncthreads();   // drains stage(t) (vmcnt) + all reads of buf[cur^1]
    if (t + 1 < nT) {  // prefetch next tile into the other buffer
      const int kt1 = (t + 1) * 64, nxt = cur ^ 1;
      load_lds16(kbase + (size_t)(kt1 + srow) * D_MODEL + scol,      &Ks[nxt][wave * 512]);
      load_lds16(kbase + (size_t)(kt1 + 32 + srow) * D_MODEL + scol, &Ks[nxt][2048 + wave * 512]);
      load_lds16(vbase + (size_t)srow * SEQQ + kt1 + scol,           &Vs[nxt][wave * 512]);
      load_lds16(vbase + (size_t)(32 + srow) * SEQQ + kt1 + scol,    &Vs[nxt][2048 + wave * 512]);
    }
    const int kt = t * 64;

    // K fragments ([key=l15][d=quad*8+j]), shared by both q-tiles
    short8 kf[4][2];
#pragma unroll
    for (int ni = 0; ni < 4; ++ni)
#pragma unroll
      for (int ks = 0; ks < 2; ++ks)
        kf[ni][ks] = *(const short8*)&Ks[cur][(ni * 16 + l15) * 64 +
                                            ((ks * 32 + quad * 8) ^ ((l15 & 7) * 8))];
    // V fragments ([d=l15][key=quad*8+j]), shared by both q-tiles
    short8 vf[2][4];
#pragma unroll
    for (int kc = 0; kc < 2; ++kc)
#pragma unroll
      for (int di = 0; di < 4; ++di)
        vf[kc][di] = *(const short8*)&Vs[cur][(di * 16 + l15) * 64 +
                                             ((kc * 32 + quad * 8) ^ ((l15 & 7) * 8))];

    const bool doA = (t <= p);   // block-uniform
    if (doA) {
      floatx4 st[4];   // S^T: row=key (quad*4+r, tile ni), col=q (l15)
#pragma unroll
      for (int ni = 0; ni < 4; ++ni) {
        floatx4 s = (floatx4){0.f, 0.f, 0.f, 0.f};
        s = mfma16(kf[ni][0], qfA[0], s);
        s = mfma16(kf[ni][1], qfA[1], s);
        st[ni] = s;
      }
      if (t == p) {   // diagonal tile of A: mask key > q
        const int qg = qwA + l15;
#pragma unroll
        for (int ni = 0; ni < 4; ++ni) {
          const int kg = kt + ni * 16 + quad * 4;
#pragma unroll
          for (int r = 0; r < 4; ++r)
            if (kg + r > qg) st[ni][r] = -1e30f;
        }
      }
      softmax_pack(st, lAp, pswA, quad, l15);
    }
    {
      floatx4 st[4];
#pragma unroll
      for (int ni = 0; ni < 4; ++ni) {
        floatx4 s = (floatx4){0.f, 0.f, 0.f, 0.f};
        s = mfma16(kf[ni][0], qfB[0], s);   // fills pswA write latency
        s = mfma16(kf[ni][1], qfB[1], s);
        st[ni] = s;
      }
      if (t == nT - 1) {   // diagonal tile of B
        const int qg = qwB + l15;
#pragma unroll
        for (int ni = 0; ni < 4; ++ni) {
          const int kg = kt + ni * 16 + quad * 4;
#pragma unroll
          for (int r = 0; r < 4; ++r)
            if (kg + r > qg) st[ni][r] = -1e30f;
        }
      }
      softmax_pack(st, lBp, pswB, quad, l15);
    }
    asm volatile("s_waitcnt lgkmcnt(0)" ::: "memory");  // single wait per iter
    if (doA) pv_mfma(accA, pswA, vf, quad, l15);
    pv_mfma(accB, pswB, vf, quad, l15);
  }

  // l reduce: across the 4 quad groups (same l15) -> every lane holds l(q=l15)
  lAp += __shfl_xor(lAp, 16); lAp += __shfl_xor(lAp, 32);
  lBp += __shfl_xor(lBp, 16); lBp += __shfl_xor(lBp, 32);

  // epilogue: O rows q=quad*4+r, cols d=di*16+l15; l for row via shfl
  {
    u16* orow = O + (size_t)(b * SEQQ + qwA + quad * 4) * D_MODEL + h * HDIM + l15;
#pragma unroll
    for (int r = 0; r < 4; ++r) {
      const float inv = 1.0f / __shfl(lAp, quad * 4 + r, 16);
#pragma unroll
      for (int di = 0; di < 4; ++di)
        orow[(size_t)r * D_MODEL + di * 16] = f2bf(accA[di][r] * inv);
    }
  }
  {
    u16* orow = O + (size_t)(b * SEQQ + qwB + quad * 4) * D_MODEL + h * HDIM + l15;
#pragma unroll
    for (int r = 0; r < 4; ++r) {
      const float inv = 1.0f / __shfl(lBp, quad * 4 + r, 16);
#pragma unroll
      for (int di = 0; di < 4; ++di)
        orow[(size_t)r * D_MODEL + di * 16] = f2bf(accB[di][r] * inv);
    }
  }
}

// ---------------------------------------------------------------- launch
extern "C" void kernel_launch(void* const* d_in, const int* in_sizes, int n_in,
                              void* d_out, int out_size, void* d_ws, size_t ws_size,
                              hipStream_t stream) {
  const float* X  = (const float*)d_in[0];
  const float* Wq = (const float*)d_in[1];
  const float* Wk = (const float*)d_in[2];
  const float* Wv = (const float*)d_in[3];
  const float* Wo = (const float*)d_in[4];
  const float* bo = (const float*)d_in[5];
  float* out = (float*)d_out;

  u16* ws = (u16*)d_ws;
  const size_t NE = (size_t)MTOT * D_MODEL;    // 8,388,608
  u16* Xb  = ws;
  u16* Qb  = Xb + NE;
  u16* Kb  = Qb + NE;
  u16* Vt  = Kb + NE;          // V projection written directly transposed
  u16* Cb  = Vt + NE;
  u16* Wqb = Cb + NE;
  u16* Wkb = Wqb + (size_t)D_MODEL * D_MODEL;
  u16* Wvb = Wkb + (size_t)D_MODEL * D_MODEL;
  u16* Wob = Wvb + (size_t)D_MODEL * D_MODEL;

  const float SCL2E = 0.18033688f;   // (1/sqrt(64)) * log2(e), folded into Q

  // 1. all casts in one launch
  k_cast_all<<<12288, 256, 0, stream>>>(X, Wq, Wk, Wv, Wo, Xb, Wqb, Wkb, Wvb, Wob);

  // 2. fused QKV projections (Q pre-scaled; V written transposed into Vt)
  k_gemm_bt<<<dim3(D_MODEL / 128, MTOT / 128, 3), 256, 0, stream>>>(
      Xb, Wqb, Wkb, Wvb, Qb, Kb, Vt, nullptr, MTOT, D_MODEL, D_MODEL, 0, SCL2E);

  // 3. causal flash attention, paired 64-row q-tiles -> Cb [8192][1024]
  k_attn<<<dim3(16, NBATCH * NHEAD), 256, 0, stream>>>(Qb, Kb, Vt, Cb);

  // 4. output projection + bias, f32 out
  k_gemm_bt<<<dim3(D_MODEL / 128, MTOT / 128, 1), 256, 0, stream>>>(
      Cb, Wob, Wob, Wob, out, out, nullptr, bo, MTOT, D_MODEL, D_MODEL, 1, 1.0f);
}